// Round 13
// baseline (320.294 us; speedup 1.0000x reference)
//
#include <hip/hip_runtime.h>
#include <hip/hip_bf16.h>
#include <math.h>

#define TT 2048
#define DD 768

typedef __bf16 bf16x8 __attribute__((ext_vector_type(8)));
typedef float f32x4 __attribute__((ext_vector_type(4)));

__device__ __forceinline__ void gload16(const void* g, void* l) {
    __builtin_amdgcn_global_load_lds(
        (const __attribute__((address_space(1))) unsigned int*)g,
        (__attribute__((address_space(3))) unsigned int*)l, 16, 0, 0);
}

__device__ __forceinline__ bf16x8 zero8() {
    bf16x8 v;
    #pragma unroll
    for (int j = 0; j < 8; ++j) v[j] = (__bf16)0.0f;
    return v;
}

// Opart slot -> pointer across the three dead-during-attention regions.
// slots: [0,192) ln1 region | [192,576) hbuf region | [576,888) Bt region
__device__ __forceinline__ const __hip_bfloat16* opart_cptr(
    const __hip_bfloat16* pA, const __hip_bfloat16* pB, const __hip_bfloat16* pC, int slot)
{
    if (slot < 192) return pA + (size_t)slot * 8192;
    if (slot < 576) return pB + (size_t)(slot - 192) * 8192;
    return pC + (size_t)(slot - 576) * 8192;
}

// ---------------------------------------------------------------- LN body (fp32 in -> bf16 out)
__device__ __forceinline__ void ln_body(const float* __restrict__ in,
    const float* __restrict__ g, const float* __restrict__ b,
    __hip_bfloat16* __restrict__ out, int t, int tid,
    float* ssum, float* sqsum)
{
    const float* row = in + (size_t)t * DD;
    float x0 = row[tid], x1 = row[tid + 256], x2 = row[tid + 512];
    float s = x0 + x1 + x2;
    float q = x0 * x0 + x1 * x1 + x2 * x2;
    #pragma unroll
    for (int m = 1; m < 64; m <<= 1) {
        s += __shfl_xor(s, m);
        q += __shfl_xor(q, m);
    }
    const int w = tid >> 6;
    if ((tid & 63) == 0) { ssum[w] = s; sqsum[w] = q; }
    __syncthreads();
    s = ssum[0] + ssum[1] + ssum[2] + ssum[3];
    q = sqsum[0] + sqsum[1] + sqsum[2] + sqsum[3];
    const float mean = s * (1.0f / DD);
    const float var = q * (1.0f / DD) - mean * mean;
    const float rs = rsqrtf(var + 1e-5f);
    __hip_bfloat16* orow = out + (size_t)t * DD;
    orow[tid]       = __float2bfloat16((x0 - mean) * rs * g[tid]       + b[tid]);
    orow[tid + 256] = __float2bfloat16((x1 - mean) * rs * g[tid + 256] + b[tid + 256]);
    orow[tid + 512] = __float2bfloat16((x2 - mean) * rs * g[tid + 512] + b[tid + 512]);
}

__global__ __launch_bounds__(256) void ln_kernel(const float* __restrict__ in,
    const float* __restrict__ g, const float* __restrict__ b,
    __hip_bfloat16* __restrict__ out)
{
    __shared__ float ssum[4], sqsum[4];
    ln_body(in, g, b, out, blockIdx.x, threadIdx.x, ssum, sqsum);
}

// ------------------------------------------- castT body: fp32 [K,N] -> bf16 [N,K], 32x32 tile
__device__ __forceinline__ void castT_body(const float* __restrict__ in,
    __hip_bfloat16* __restrict__ out, int K, int N, int bx, int by, int tid,
    float (*tt)[33])
{
    const int n0 = bx << 5, k0 = by << 5;
    const int tx = tid & 31, ty = tid >> 5;
    #pragma unroll
    for (int i = 0; i < 32; i += 8)
        tt[ty + i][tx] = in[(size_t)(k0 + ty + i) * N + n0 + tx];
    __syncthreads();
    #pragma unroll
    for (int i = 0; i < 32; i += 8)
        out[(size_t)(n0 + ty + i) * K + k0 + tx] = __float2bfloat16(tt[tx][ty + i]);
}

// ------------------------------------------- fused phase-0 prep + ln1 (R21: launch fusion)
// grid 4569: [0,2048) ln1 | [2048,3776) qkv_w castT | [3776,4352) gvw castT | [4352,4569) wcat
__global__ __launch_bounds__(256) void fused0_kernel(
    const float* __restrict__ x, const float* __restrict__ ln1_g, const float* __restrict__ ln1_b,
    __hip_bfloat16* __restrict__ ln1,
    const float* __restrict__ qkv_w, const float* __restrict__ gvw,
    const float* __restrict__ w2w, const float* __restrict__ w1w,
    const float* __restrict__ w1r, const float* __restrict__ w2r,
    const float* __restrict__ gw, const float* __restrict__ qkv_b,
    const float* __restrict__ gvb,
    __hip_bfloat16* __restrict__ Bt, float* __restrict__ bias3)
{
    __shared__ float tt[32][33];
    const int bid = blockIdx.x;
    const int tid = threadIdx.x;
    if (bid < 2048) { ln_body(x, ln1_g, ln1_b, ln1, bid, tid, (float*)&tt[0][0], (float*)&tt[1][0]); return; }
    const int pb = bid - 2048;
    if (pb < 1728)      { castT_body(qkv_w, Bt, 768, 2304, pb % 72, pb / 72, tid, tt); return; }
    else if (pb < 2304) { int b = pb - 1728; castT_body(gvw, Bt + (size_t)2304 * 768, 768, 768, b % 24, b / 24, tid, tt); return; }
    const int wb = pb - 2304;
    if (wb >= 204) {   // bias concat: 13 blocks x 256 = 3328
        const int idx = (wb - 204) * 256 + tid;
        float v = (idx < 2304) ? qkv_b[idx] : ((idx < 3072) ? gvb[idx - 2304] : 0.f);
        bias3[idx] = v;
        return;
    }
    const float* src; int col, stride;
    if (wb < 48)       { src = w2w; col = wb;       stride = 48; }
    else if (wb < 96)  { src = w1w; col = wb - 48;  stride = 48; }
    else if (wb < 144) { src = w1r; col = wb - 96;  stride = 48; }
    else if (wb < 192) { src = w2r; col = wb - 144; stride = 48; }
    else               { src = gw;  col = wb - 192; stride = 12; }
    #pragma unroll
    for (int i = 0; i < 3; ++i) {
        const int k = tid + (i << 8);
        Bt[(size_t)(3072 + wb) * 768 + k] = __float2bfloat16(src[(size_t)k * stride + col]);
    }
}

// ------------------------------------------- phase-1 prep: ow/fcw/pw castT
// grid 5184: [0,576) ow->o0 | [576,2880) fcw->o1 | [2880,5184) pw->o2
__global__ __launch_bounds__(256) void prep1_kernel(
    const float* __restrict__ w0, const float* __restrict__ w1, const float* __restrict__ w2,
    __hip_bfloat16* __restrict__ o0, __hip_bfloat16* __restrict__ o1,
    __hip_bfloat16* __restrict__ o2)
{
    __shared__ float tt[32][33];
    const int bid = blockIdx.x;
    const int tid = threadIdx.x;
    if (bid < 576)       { castT_body(w0, o0, 768, 768, bid % 24, bid / 24, tid, tt); }
    else if (bid < 2880) { int b = bid - 576;  castT_body(w1, o1, 768, 3072, b % 96, b / 96, tid, tt); }
    else                 { int b = bid - 2880; castT_body(w2, o2, 3072, 768, b % 24, b / 24, tid, tt); }
}

// ---------------------------------------------------------------- MFMA GEMM (128x64 tile, BK=96)
// R25: BK 64 -> 96 (three [*][32] subtiles per staging phase; per-subtile
// swizzle unchanged). Drain pairs 12 -> 8 at K=768. LDS 36.9 KB -> still
// 4 blocks/CU by LDS (R7 occupancy-cliff avoided); acc 32 VGPR. R12's
// BK 32->64 measured -19.5 us (drains 24->12) -- this takes the next 1/3.
__device__ __forceinline__ float gelu_f(float x) {
    float u = 0.7978845608028654f * (x + 0.044715f * x * x * x);
    return 0.5f * x * (1.0f + tanhf(u));
}

__global__ __launch_bounds__(256) void mgemm_kernel(
    const __hip_bfloat16* __restrict__ A, const __hip_bfloat16* __restrict__ Bt,
    const float* __restrict__ bias, const float* __restrict__ resid,
    void* __restrict__ Cout, float* __restrict__ Pb0, float* __restrict__ Pb1,
    int M, int N, int K, int kz, int epi, int omode)
{
    __shared__ __hip_bfloat16 As[3 * 128 * 32];
    __shared__ __hip_bfloat16 Bs[3 * 64 * 32];
    const int tid = threadIdx.x;
    const int lane = tid & 63, w = tid >> 6;
    const int colBase = blockIdx.x << 6, rowBase = blockIdx.y << 7;
    const int z = blockIdx.z;
    const int Kc = K / kz, koff = z * Kc;

    const int lr = lane >> 2, pc = lane & 3;
    const int n = lane & 15, quad = lane >> 4;

    const int sr0 = (w << 4) + lr;
    const int sr1 = 64 + sr0;
    const int sc0 = (pc ^ ((sr0 >> 1) & 3)) << 3;

    f32x4 acc[2][4];
    #pragma unroll
    for (int i = 0; i < 2; ++i)
        #pragma unroll
        for (int j = 0; j < 4; ++j) acc[i][j] = (f32x4){0.f, 0.f, 0.f, 0.f};

    const int ar0 = (w << 5) + n;
    const int ar1 = ar0 + 16;
    const int ap0 = (quad ^ ((ar0 >> 1) & 3)) << 3;
    const int ap1 = (quad ^ ((ar1 >> 1) & 3)) << 3;

    for (int kk = koff; kk < koff + Kc; kk += 96) {
        __syncthreads();
        // three K-subtiles; layouts [3][128][32] / [3][64][32]
        #pragma unroll
        for (int s = 0; s < 3; ++s) {
            const int ks = kk + (s << 5);
            gload16(A  + (size_t)(rowBase + sr0) * K + ks + sc0, &As[(s << 12) + (w << 4) * 32]);
            gload16(A  + (size_t)(rowBase + sr1) * K + ks + sc0, &As[(s << 12) + (64 + (w << 4)) * 32]);
            gload16(Bt + (size_t)(colBase + sr0) * K + ks + sc0, &Bs[(s << 11) + (w << 4) * 32]);
        }
        __syncthreads();

        #pragma unroll
        for (int s = 0; s < 3; ++s) {
            const int aoff = s << 12;           // s * 128 * 32
            const int boff = s << 11;           // s * 64 * 32
            bf16x8 a0 = *(const bf16x8*)&As[aoff + ar0 * 32 + ap0];
            bf16x8 a1 = *(const bf16x8*)&As[aoff + ar1 * 32 + ap1];
            #pragma unroll
            for (int j = 0; j < 4; ++j) {
                const int rb = (j << 4) + n;
                bf16x8 bfj = *(const bf16x8*)&Bs[boff + rb * 32 + ((quad ^ ((rb >> 1) & 3)) << 3)];
                acc[0][j] = __builtin_amdgcn_mfma_f32_16x16x32_bf16(a0, bfj, acc[0][j], 0, 0, 0);
                acc[1][j] = __builtin_amdgcn_mfma_f32_16x16x32_bf16(a1, bfj, acc[1][j], 0, 0, 0);
            }
        }
    }

    if (kz == 1) {
        #pragma unroll
        for (int j = 0; j < 4; ++j) {
            const int col = colBase + (j << 4) + n;
            const float bj = bias ? bias[col] : 0.f;
            #pragma unroll
            for (int i = 0; i < 2; ++i) {
                #pragma unroll
                for (int r = 0; r < 4; ++r) {
                    const int row = rowBase + (w << 5) + (i << 4) + (quad << 2) + r;
                    float v = acc[i][j][r] + bj;
                    if (epi == 1) v = gelu_f(v);
                    else if (epi == 2) v += resid[(size_t)row * N + col];
                    if (omode == 1) ((__hip_bfloat16*)Cout)[(size_t)row * N + col] = __float2bfloat16(v);
                    else ((float*)Cout)[(size_t)row * N + col] = v;
                }
            }
        }
    } else {
        float* P = (z == 0) ? Pb0 : Pb1;
        #pragma unroll
        for (int j = 0; j < 4; ++j) {
            const int col = colBase + (j << 4) + n;
            #pragma unroll
            for (int i = 0; i < 2; ++i) {
                #pragma unroll
                for (int r = 0; r < 4; ++r) {
                    const int row = rowBase + (w << 5) + (i << 4) + (quad << 2) + r;
                    P[(size_t)row * N + col] = acc[i][j][r];
                }
            }
        }
    }
}

// ------------------------------------------- split-K reduce: out = p0+p1+bias+resid (fp32)
__global__ __launch_bounds__(256) void kred_kernel(
    const float* __restrict__ p0, const float* __restrict__ p1,
    const float* __restrict__ bias, const float* __restrict__ resid,
    float* __restrict__ out, int N)
{
    const int base = (blockIdx.x * 256 + threadIdx.x) << 2;
    float4 a = *(const float4*)&p0[base];
    float4 b = *(const float4*)&p1[base];
    float4 bi = *(const float4*)&bias[base % N];
    float4 rs = *(const float4*)&resid[base];
    float4 o;
    o.x = a.x + b.x + bi.x + rs.x;
    o.y = a.y + b.y + bi.y + rs.y;
    o.z = a.z + b.z + bi.z + rs.z;
    o.w = a.w + b.w + bi.w + rs.w;
    *(float4*)&out[base] = o;
}

// ------------------------------------------------- exterior product helper
__device__ __forceinline__ void exterior6(const float* a, const float* b, float* L) {
    L[0] = a[0] * b[1] - a[1] * b[0];
    L[1] = a[0] * b[2] - a[2] * b[0];
    L[2] = a[0] * b[3] - a[3] * b[0];
    L[3] = a[1] * b[2] - a[2] * b[1];
    L[4] = a[1] * b[3] - a[3] * b[1];
    L[5] = a[2] * b[3] - a[3] * b[2];
    float n = sqrtf(L[0]*L[0] + L[1]*L[1] + L[2]*L[2] + L[3]*L[3] + L[4]*L[4] + L[5]*L[5]);
    float inv = 1.f / fmaxf(n, 1e-12f);
    #pragma unroll
    for (int p = 0; p < 6; ++p) L[p] *= inv;
}

// ------------------------------------------- fused extgate (4 tok/block) + vt (R21)
// grid 1280: [0,512) extgate x4 | [512,896) VT | [896,1280) GVT
__global__ __launch_bounds__(256) void fusedev_kernel(
    const __hip_bfloat16* __restrict__ qkvAll, const float* __restrict__ gb,
    __hip_bfloat16* __restrict__ rlb, __hip_bfloat16* __restrict__ jwb,
    float* __restrict__ gate,
    __hip_bfloat16* __restrict__ VT, __hip_bfloat16* __restrict__ GVT)
{
    __shared__ __hip_bfloat16 tile[64][72];
    const int bid = blockIdx.x;
    const int tid = threadIdx.x;
    if (bid < 512) {
        const int t = (bid << 2) | (tid >> 6);
        const int lane = tid & 63;
        const __hip_bfloat16* row = qkvAll + (size_t)t * 3328 + 3072;
        if (lane < 12) {
            const int h = lane;
            float a[4], b[4], L[6];
            #pragma unroll
            for (int i = 0; i < 4; ++i) {
                a[i] = (t > 0) ? __bfloat162float(row[-3328 + 48 + h * 4 + i]) : 0.f;
                b[i] = __bfloat162float(row[h * 4 + i]);
            }
            exterior6(a, b, L);
            __hip_bfloat16* jwp = jwb + (size_t)h * 16384 + t * 8;
            jwp[0] = __float2bfloat16( L[5]); jwp[1] = __float2bfloat16(-L[4]);
            jwp[2] = __float2bfloat16( L[3]); jwp[3] = __float2bfloat16( L[2]);
            jwp[4] = __float2bfloat16(-L[1]); jwp[5] = __float2bfloat16( L[0]);
            jwp[6] = __float2bfloat16(0.f);   jwp[7] = __float2bfloat16(0.f);
            #pragma unroll
            for (int i = 0; i < 4; ++i) {
                a[i] = __bfloat162float(row[96 + h * 4 + i]);
                b[i] = __bfloat162float(row[144 + h * 4 + i]);
            }
            exterior6(a, b, L);
            __hip_bfloat16* rlp = rlb + (size_t)h * 16384 + t * 8;
            #pragma unroll
            for (int p = 0; p < 6; ++p) rlp[p] = __float2bfloat16(L[p]);
            rlp[6] = __float2bfloat16(0.f); rlp[7] = __float2bfloat16(0.f);
        }
        if (lane == 32) {
            float g = 0.f;
            #pragma unroll
            for (int i = 0; i < 12; ++i)
                g += 1.f / (1.f + __expf(-(__bfloat162float(row[192 + i]) + gb[i])));
            gate[t] = g * (1.f / 12.f);
        }
        return;
    }
    // ---- vt part
    const int b = bid - 512;
    const bool isGV = (b >= 384);
    const int rem = isGV ? (b - 384) : b;
    const int h = rem >> 5;
    const int s0 = (rem & 31) << 6;
    const __hip_bfloat16* src = qkvAll + (isGV ? 2304 : 1536) + h * 64;
    __hip_bfloat16* dst = (isGV ? GVT : VT) + (size_t)h * 131072;
    const int r = tid >> 2, c = (tid & 3) << 3;
    *(bf16x8*)&tile[r][c]      = *(const bf16x8*)&src[(size_t)(s0 + r) * 3328 + c];
    *(bf16x8*)&tile[r][c + 32] = *(const bf16x8*)&src[(size_t)(s0 + r) * 3328 + c + 32];
    __syncthreads();
    __hip_bfloat16 tmp[8];
    #pragma unroll
    for (int j = 0; j < 8; ++j) tmp[j] = tile[c + j][r];
    *(bf16x8*)&dst[(size_t)r * 2048 + s0 + c] = *(const bf16x8*)tmp;
    #pragma unroll
    for (int j = 0; j < 8; ++j) tmp[j] = tile[c + 32 + j][r];
    *(bf16x8*)&dst[(size_t)r * 2048 + s0 + c + 32] = *(const bf16x8*)tmp;
}

// ---------------------------------------------------------------- MFMA dual-path flash attention
// R8's mattn verbatim (measured 55.4-55.6 us; staged pipeline load-bearing
// per R5 ablation; exp2f/cap-8 reverted per R10). 34.8 KB LDS, 4 blocks/CU.
__global__ __launch_bounds__(256) void mattn_kernel(
    const __hip_bfloat16* __restrict__ qkvAll, const __hip_bfloat16* __restrict__ VT,
    const __hip_bfloat16* __restrict__ GVT, const __hip_bfloat16* __restrict__ rlb,
    const __hip_bfloat16* __restrict__ jwb, const float* __restrict__ gate,
    const float* __restrict__ inc_scale, __hip_bfloat16* __restrict__ comb,
    __hip_bfloat16* __restrict__ OpA, __hip_bfloat16* __restrict__ OpB,
    __hip_bfloat16* __restrict__ OpC, float* __restrict__ stats)
{
    __shared__ __hip_bfloat16 Ks0[2048], Ks1[2048];
    __shared__ __hip_bfloat16 VTs0[2048], VTs1[2048];
    __shared__ __hip_bfloat16 GVTs0[2048], GVTs1[2048];
    __shared__ __hip_bfloat16 JWs[64][8];
    __shared__ __bf16 Ps[64][72];

    const int j = blockIdx.x;          // 0..73
    const int hh = blockIdx.y;
    int qt = 0, acc = 0, nc = 1;
    #pragma unroll 1
    for (;;) {
        nc = (qt + 9) / 9;             // ceil((qt+1)/9)
        if (j < acc + nc) break;
        acc += nc; ++qt;
    }
    const int c = j - acc;
    const int q0 = qt << 6;
    const int nk = qt + 1;
    const int ktb = c * nk / nc;
    const int kte = (c + 1) * nk / nc - 1;
    const int tid = threadIdx.x;
    const int w = tid >> 6, lane = tid & 63;
    const int n = lane & 15, quad = lane >> 4;

    const int qrow = q0 + (w << 4) + n;
    const size_t qb = (size_t)qrow * 3328 + hh * 64;
    bf16x8 af0 = *(const bf16x8*)&qkvAll[qb + (quad << 3)];
    bf16x8 af1 = *(const bf16x8*)&qkvAll[qb + 32 + (quad << 3)];
    bf16x8 rlA = zero8();
    if (quad == 0) rlA = *(const bf16x8*)&rlb[(size_t)hh * 16384 + (size_t)qrow * 8];
    const float isc = inc_scale[hh];
    const float mgc = fabsf(isc);
    const size_t vbase = (size_t)hh * 131072;

    const int sRow = tid >> 2, sc = tid & 3;
    const int sPos = ((sc ^ ((sRow >> 1) & 3)) << 3);
    const int sOff = sc << 3;

    f32x4 Os[4], Og[4];
    float m_s[4], lsp[4], lgp[4];
    #pragma unroll
    for (int r = 0; r < 4; ++r) {
        m_s[r] = -1e30f; lsp[r] = 0.f; lgp[r] = 0.f;
        Os[r] = (f32x4){0.f, 0.f, 0.f, 0.f};
        Og[r] = (f32x4){0.f, 0.f, 0.f, 0.f};
    }

    bf16x8 rK0, rK1, rV0, rV1, rG0, rG1, rJ = zero8();
    {
        const int k0 = ktb << 6;
        const size_t kb = (size_t)(k0 + sRow) * 3328 + 768 + hh * 64;
        const size_t vb = vbase + (size_t)sRow * 2048 + k0;
        rK0 = *(const bf16x8*)&qkvAll[kb + sOff];
        rK1 = *(const bf16x8*)&qkvAll[kb + sOff + 32];
        rV0 = *(const bf16x8*)&VT[vb + sOff];
        rV1 = *(const bf16x8*)&VT[vb + sOff + 32];
        rG0 = *(const bf16x8*)&GVT[vb + sOff];
        rG1 = *(const bf16x8*)&GVT[vb + sOff + 32];
        if (tid < 64) rJ = *(const bf16x8*)&jwb[(size_t)hh * 16384 + (size_t)(k0 + tid) * 8];
    }

    for (int kt = ktb; kt <= kte; ++kt) {
        const int k0 = kt << 6;
        __syncthreads();   // prior reads of LDS tiles done
        *(bf16x8*)&Ks0[sRow * 32 + sPos]  = rK0;
        *(bf16x8*)&Ks1[sRow * 32 + sPos]  = rK1;
        *(bf16x8*)&VTs0[sRow * 32 + sPos] = rV0;
        *(bf16x8*)&VTs1[sRow * 32 + sPos] = rV1;
        *(bf16x8*)&GVTs0[sRow * 32 + sPos] = rG0;
        *(bf16x8*)&GVTs1[sRow * 32 + sPos] = rG1;
        if (tid < 64) *(bf16x8*)&JWs[tid][0] = rJ;
        if (kt < kte) {
            const int k1 = (kt + 1) << 6;
            const size_t kb = (size_t)(k1 + sRow) * 3328 + 768 + hh * 64;
            const size_t vb = vbase + (size_t)sRow * 2048 + k1;
            rK0 = *(const bf16x8*)&qkvAll[kb + sOff];
            rK1 = *(const bf16x8*)&qkvAll[kb + sOff + 32];
            rV0 = *(const bf16x8*)&VT[vb + sOff];
            rV1 = *(const bf16x8*)&VT[vb + sOff + 32];
            rG0 = *(const bf16x8*)&GVT[vb + sOff];
            rG1 = *(const bf16x8*)&GVT[vb + sOff + 32];
            if (tid < 64) rJ = *(const bf16x8*)&jwb[(size_t)hh * 16384 + (size_t)(k1 + tid) * 8];
        }
        __syncthreads();   // LDS tiles ready

        // ---- S = QK^T (std) and RL*JW (geo)
        f32x4 Ss[4], Sg[4];
        #pragma unroll
        for (int t = 0; t < 4; ++t) {
            Ss[t] = (f32x4){0.f, 0.f, 0.f, 0.f};
            Sg[t] = (f32x4){0.f, 0.f, 0.f, 0.f};
        }
        #pragma unroll
        for (int t = 0; t < 4; ++t) {
            const int krow = (t << 4) + n;
            const int kpos = ((quad ^ ((krow >> 1) & 3)) << 3);
            bf16x8 kb0 = *(const bf16x8*)&Ks0[krow * 32 + kpos];
            bf16x8 kb1 = *(const bf16x8*)&Ks1[krow * 32 + kpos];
            Ss[t] = __builtin_amdgcn_mfma_f32_16x16x32_bf16(af0, kb0, Ss[t], 0, 0, 0);
            Ss[t] = __builtin_amdgcn_mfma_f32_16x16x32_bf16(af1, kb1, Ss[t], 0, 0, 0);
            bf16x8 jb = zero8();
            if (quad == 0) jb = *(const bf16x8*)&JWs[krow][0];
            Sg[t] = __builtin_amdgcn_mfma_f32_16x16x32_bf16(rlA, jb, Sg[t], 0, 0, 0);
        }
        #pragma unroll
        for (int t = 0; t < 4; ++t) {
            #pragma unroll
            for (int r = 0; r < 4; ++r) { Ss[t][r] *= 0.125f; Sg[t][r] *= isc; }
        }
        if (kt == qt) {
            #pragma unroll
            for (int t = 0; t < 4; ++t) {
                const int sg = k0 + (t << 4) + n;
                #pragma unroll
                for (int r = 0; r < 4; ++r) {
                    const int qg = q0 + (w << 4) + (quad << 2) + r;
                    if (sg > qg) { Ss[t][r] = -1e30f; Sg[t][r] = -1e30f; }
                }
            }
        }

        // ---- softmax: std max-reduce; sums lane-local
        #pragma unroll
        for (int r = 0; r < 4; ++r) {
            float mx = fmaxf(fmaxf(Ss[0][r], Ss[1][r]), fmaxf(Ss[2][r], Ss[3][r]));
            #pragma unroll
            for (int mk = 1; mk < 16; mk <<= 1) mx = fmaxf(mx, __shfl_xor(mx, mk));
            float mnew = fmaxf(m_s[r], mx);
            float alpha = __expf(m_s[r] - mnew);
            m_s[r] = mnew;
            float sm = 0.f;
            #pragma unroll
            for (int t = 0; t < 4; ++t) { Ss[t][r] = __expf(Ss[t][r] - mnew); sm += Ss[t][r]; }
            lsp[r] = lsp[r] * alpha + sm;
            #pragma unroll
            for (int t = 0; t < 4; ++t) Os[t][r] *= alpha;

            float smg = 0.f;
            #pragma unroll
            for (int t = 0; t < 4; ++t) { Sg[t][r] = __expf(Sg[t][r] - mgc); smg += Sg[t][r]; }
            lgp[r] += smg;
        }

        // ---- std P -> LDS (wave-local), fence, std PV
        #pragma unroll
        for (int t = 0; t < 4; ++t) {
            #pragma unroll
            for (int r = 0; r < 4; ++r)
                Ps[(w << 4) + (quad << 2) + r][(t << 4) + n] = (__bf16)Ss[t][r];
        }
        asm volatile("s_waitcnt lgkmcnt(0)" ::: "memory");
        #pragma unroll
        for (int st = 0; st < 2; ++st) {
            bf16x8 ap = *(const bf16x8*)&Ps[(w << 4) + n][(st << 5) + (quad << 3)];
            const __hip_bfloat16* Vh = st ? VTs1 : VTs0;
            #pragma unroll
            for (int dt = 0; dt < 4; ++dt) {
                const int vrow = (dt << 4) + n;
                const int vpos = ((quad ^ ((vrow >> 1) & 3)) << 3);
                bf16x8 vb2 = *(const bf16x8*)&Vh[vrow * 32 + vpos];
                Os[dt] = __builtin_amdgcn_mfma_f32_16x16x32_bf16(ap, vb2, Os[dt], 0, 0, 0);
            }
        }
        asm volatile("s_waitcnt lgkmcnt(0)" ::: "memory");   // P reads drained before overwrite

        // ---- geo P -> same LDS buffer, fence, geo PV
        #pragma unroll
        for (int t = 0; t < 4; ++t) {
            #pragma unroll
            for (int r = 0; r < 4; ++r)
                Ps[(w << 4) + (quad << 2) + r][(t << 4) + n] = (__bf16)Sg[t][r];
        }
        asm volatile("s_waitcnt lgkmcnt(0)" ::: "memory");
        #pragma unroll
        for (int st = 0; st < 2; ++st) {
            bf16x8 gp = *(const bf16x8*)&Ps[(w << 4) + n][(st << 5) + (quad << 3)];
            const __hip_bfloat16* Gh = st ? GVTs1 : GVTs0;
            #pragma unroll
            for (int dt = 0; dt < 4; ++dt) {
                const int vrow = (dt << 4) + n;
                const int vpos = ((quad ^ ((vrow >> 1) & 3)) << 3);
                bf16x8 gb2 = *(const bf16x8*)&Gh[vrow * 32 + vpos];
                Og[dt] = __builtin_amdgcn_mfma_f32_16x16x32_bf16(gp, gb2, Og[dt], 0, 0, 0);
            }
        }
    }

    // ---- final l_s / l_g reduction
    float l_s[4], l_g[4];
    #pragma unroll
    for (int r = 0; r < 4; ++r) {
        float ls = lsp[r], lg = lgp[r];
        #pragma unroll
        for (int mk = 1; mk < 16; mk <<= 1) {
            ls += __shfl_xor(ls, mk);
            lg += __shfl_xor(lg, mk);
        }
        l_s[r] = ls; l_g[r] = lg;
    }

    if (nc == 1) {
        #pragma unroll
        for (int r = 0; r < 4; ++r) {
            const int row = q0 + (w << 4) + (quad << 2) + r;
            const float g = gate[row];
            const float invs = (1.f - g) / l_s[r], invg = g / l_g[r];
            #pragma unroll
            for (int dt = 0; dt < 4; ++dt) {
                float val = Os[dt][r] * invs + Og[dt][r] * invg;
                comb[(size_t)row * DD + hh * 64 + (dt << 4) + n] = __float2bfloat16(val);
            }
        }
    } else {
        const int slot = hh * 74 + acc + c;
        __hip_bfloat16* op = (__hip_bfloat16*)opart_cptr(OpA, OpB, OpC, slot);
        float* st = stats + (size_t)slot * 256;
        #pragma unroll
        for (int r = 0; r < 4; ++r) {
            const int rloc = (w << 4) + (quad << 2) + r;
            #pragma unroll
            for (int dt = 0; dt < 4; ++dt) {
                const int col = (dt << 4) + n;
                op[rloc * 128 + col]      = __float2bfloat16(Os[dt][r]);
                op[rloc * 128 + 64 + col] = __float2bfloat16(Og[dt][r]);
            }
            if (n == 0) {
                st[rloc * 4 + 0] = m_s[r]; st[rloc * 4 + 1] = l_s[r];
                st[rloc * 4 + 2] = mgc;    st[rloc * 4 + 3] = l_g[r];
            }
        }
    }
}

// ------------------------------------------- combine 2-4 K-chunks (qt>=9)
__global__ __launch_bounds__(256) void acomb_kernel(
    const __hip_bfloat16* __restrict__ OpA, const __hip_bfloat16* __restrict__ OpB,
    const __hip_bfloat16* __restrict__ OpC, const float* __restrict__ stats,
    const float* __restrict__ gate, __hip_bfloat16* __restrict__ comb)
{
    const int qt = 9 + blockIdx.x;     // 9..31
    const int h = blockIdx.y;
    const int nc = (qt + 9) / 9;       // 2..4
    int acc = 0;
    #pragma unroll 1
    for (int q = 0; q < qt; ++q) acc += (q + 9) / 9;
    const int sb = h * 74 + acc;
    const int tid = threadIdx.x;
    const int rloc = tid >> 2;
    const int cseg = (tid & 3) << 4;
    const int row = (qt << 6) + rloc;
    float ms = -1e30f, mg = -1e30f;
    for (int c = 0; c < nc; ++c) {
        const float* st = stats + (size_t)(sb + c) * 256 + rloc * 4;
        ms = fmaxf(ms, st[0]);
        mg = fmaxf(mg, st[2]);
    }
    float wsc[4], wgc[4];
    float ls = 0.f, lg = 0.f;
    for (int c = 0; c < nc; ++c) {
        const float* st = stats + (size_t)(sb + c) * 256 + rloc * 4;
        wsc[c] = __expf(st[0] - ms); ls += st[1] * wsc[c];
        wgc[c] = __expf(st[2] - mg); lg += st[3] * wgc[c];
    }
    const float g = gate[row];
    const float fs = (1.f - g) / ls, fg = g / lg;
    #pragma unroll
    for (int cc = 0; cc < 16; ++cc) {
        const int col = cseg + cc;
        float os = 0.f, og = 0.f;
        for (int c = 0; c < nc; ++c) {
            const __hip_bfloat16* op = opart_cptr(OpA, OpB, OpC, sb + c) + rloc * 128;
            os += __bfloat162float(op[col]) * wsc[c];
            og += __bfloat162float(op[64 + col]) * wgc[c];
        }
        comb[(size_t)row * DD + h * 64 + col] = __float2bfloat16(os * fs + og * fg);
    }
}

// ---------------------------------------------------------------- launch
extern "C" void kernel_launch(void* const* d_in, const int* in_sizes, int n_in,
                              void* d_out, int out_size, void* d_ws, size_t ws_size,
                              hipStream_t stream) {
    (void)in_sizes; (void)n_in; (void)out_size; (void)ws_size;
    const float* x      = (const float*)d_in[0];
    const float* ln1_g  = (const float*)d_in[1];
    const float* ln1_b  = (const float*)d_in[2];
    const float* qkv_w  = (const float*)d_in[3];
    const float* qkv_b  = (const float*)d_in[4];
    const float* w1w    = (const float*)d_in[5];
    const float* w2w    = (const float*)d_in[6];
    const float* w1r    = (const float*)d_in[7];
    const float* w2r    = (const float*)d_in[8];
    const float* gvw    = (const float*)d_in[9];
    const float* gvb    = (const float*)d_in[10];
    const float* gw     = (const float*)d_in[11];
    const float* gb     = (const float*)d_in[12];
    const float* isc    = (const float*)d_in[13];
    const float* ow     = (const float*)d_in[14];
    const float* ob     = (const float*)d_in[15];
    const float* ln2_g  = (const float*)d_in[16];
    const float* ln2_b  = (const float*)d_in[17];
    const float* fcw    = (const float*)d_in[18];
    const float* fcb    = (const float*)d_in[19];
    const float* pw     = (const float*)d_in[20];
    const float* pb     = (const float*)d_in[21];
    float* out = (float*)d_out;
    char* wsb  = (char*)d_ws;

    // ---- workspace layout
    __hip_bfloat16* qkvAll = (__hip_bfloat16*)(wsb + 0);         // 2048x3328 bf16 = 13631488
    __hip_bfloat16* VTb    = (__hip_bfloat16*)(wsb + 13631488);  // 3145728
    __hip_bfloat16* GVTb   = (__hip_bfloat16*)(wsb + 16777216);  // 3145728
    __hip_bfloat16* rlb    = (__hip_bfloat16*)(wsb + 19922944);  // 393216
    __hip_bfloat16* jwb    = (__hip_bfloat16*)(wsb + 20316160);  // 393216
    float*          gate   = (float*)(wsb + 20709376);           // 8192
    __hip_bfloat16* ln1    = (__hip_bfloat16*)(wsb + 20717568);  // 3145728
    __hip_bfloat16* comb   = (__hip_bfloat16*)(wsb + 23863296);  // 3145728
    float*          hbuf   = (float*)(wsb + 27009024);           // 6291456
    __hip_bfloat16* Bt     = (__hip_bfloat16*)(wsb + 33300480);  // 3328x768 bf16 = 5111808
    float*          bias3  = (float*)(wsb + 38412288);           // 13312
    __hip_bfloat16* owt    = (__hip_bfloat16*)(wsb + 38425600);  // 1179648

    // attention-phase aliases (ln1 / hbuf / Bt dead during attention)
    __hip_bfloat16* OpA   = ln1;                   // slots [0,192)
    __hip_bfloat16* OpB   = (__hip_bfloat16*)hbuf; // slots [192,576)
    __hip_bfloat16* OpC   = Bt;                    // slots [576,888)
    float*          stats = (float*)owt;           // 888*1KB = 909312 <= 1179648

    // MLP-phase aliases
    __hip_bfloat16* fcact  = qkvAll;                             // 2048x3072 bf16 = 12582912
    __hip_bfloat16* pwt    = VTb;                                // 768x3072 bf16 = 4718592
    __hip_bfloat16* fcwt   = Bt;                                 // 3072x768 bf16 = 4718592
    float* Ppart0 = (float*)(wsb + 20717568);                    // ln1+comb = 6291456
    float* Ppart1 = (float*)(wsb + 33300480);                    // Bt..owt  = 6291456

    // fused phase-0 prep + ln1
    fused0_kernel<<<4569, 256, 0, stream>>>(x, ln1_g, ln1_b, ln1,
                                            qkv_w, gvw, w2w, w1w, w1r, w2r, gw, qkv_b, gvb,
                                            Bt, bias3);
    // fused qkv + geo_v + small-proj GEMM: [2048,768] x [768,3328] -> bf16
    mgemm_kernel<<<dim3(52, 16, 1), 256, 0, stream>>>(ln1, Bt, bias3, nullptr, qkvAll,
                                                      nullptr, nullptr, TT, 3328, 768, 1, 0, 1);
    // fused extgate + vt
    fusedev_kernel<<<1280, 256, 0, stream>>>(qkvAll, gb, rlb, jwb, gate, VTb, GVTb);
    mattn_kernel<<<dim3(74, 12), 256, 0, stream>>>(qkvAll, VTb, GVTb, rlb, jwb, gate, isc,
                                                   comb, OpA, OpB, OpC, stats);
    acomb_kernel<<<dim3(23, 12), 256, 0, stream>>>(OpA, OpB, OpC, stats, gate, comb);
    // phase-1 prep (after acomb: Bt/owt regions die)
    prep1_kernel<<<5184, 256, 0, stream>>>(ow, fcw, pw, owt, fcwt, pwt);
    mgemm_kernel<<<dim3(12, 16, 1), 256, 0, stream>>>(comb, owt, ob, x, hbuf,
                                                      nullptr, nullptr, TT, 768, 768, 1, 2, 0);
    ln_kernel<<<TT, 256, 0, stream>>>(hbuf, ln2_g, ln2_b, ln1);
    mgemm_kernel<<<dim3(48, 16, 1), 256, 0, stream>>>(ln1, fcwt, fcb, nullptr, fcact,
                                                      nullptr, nullptr, TT, 3072, 768, 1, 1, 1);
    mgemm_kernel<<<dim3(12, 16, 2), 256, 0, stream>>>(fcact, pwt, pb, nullptr, nullptr,
                                                      Ppart0, Ppart1, TT, 768, 3072, 2, 0, 0);
    kred_kernel<<<1536, 256, 0, stream>>>(Ppart0, Ppart1, pb, hbuf, out, 768);
}

// Round 14
// 315.652 us; speedup vs baseline: 1.0147x; 1.0147x over previous
//
#include <hip/hip_runtime.h>
#include <hip/hip_bf16.h>
#include <math.h>

#define TT 2048
#define DD 768

typedef __bf16 bf16x8 __attribute__((ext_vector_type(8)));
typedef float f32x4 __attribute__((ext_vector_type(4)));

__device__ __forceinline__ void gload16(const void* g, void* l) {
    __builtin_amdgcn_global_load_lds(
        (const __attribute__((address_space(1))) unsigned int*)g,
        (__attribute__((address_space(3))) unsigned int*)l, 16, 0, 0);
}

__device__ __forceinline__ bf16x8 zero8() {
    bf16x8 v;
    #pragma unroll
    for (int j = 0; j < 8; ++j) v[j] = (__bf16)0.0f;
    return v;
}

// Opart slot -> pointer across the three dead-during-attention regions.
// slots: [0,192) ln1 region | [192,576) hbuf region | [576,888) Bt region
__device__ __forceinline__ const __hip_bfloat16* opart_cptr(
    const __hip_bfloat16* pA, const __hip_bfloat16* pB, const __hip_bfloat16* pC, int slot)
{
    if (slot < 192) return pA + (size_t)slot * 8192;
    if (slot < 576) return pB + (size_t)(slot - 192) * 8192;
    return pC + (size_t)(slot - 576) * 8192;
}

// ---------------------------------------------------------------- LN body (fp32 in -> bf16 out)
__device__ __forceinline__ void ln_body(const float* __restrict__ in,
    const float* __restrict__ g, const float* __restrict__ b,
    __hip_bfloat16* __restrict__ out, int t, int tid,
    float* ssum, float* sqsum)
{
    const float* row = in + (size_t)t * DD;
    float x0 = row[tid], x1 = row[tid + 256], x2 = row[tid + 512];
    float s = x0 + x1 + x2;
    float q = x0 * x0 + x1 * x1 + x2 * x2;
    #pragma unroll
    for (int m = 1; m < 64; m <<= 1) {
        s += __shfl_xor(s, m);
        q += __shfl_xor(q, m);
    }
    const int w = tid >> 6;
    if ((tid & 63) == 0) { ssum[w] = s; sqsum[w] = q; }
    __syncthreads();
    s = ssum[0] + ssum[1] + ssum[2] + ssum[3];
    q = sqsum[0] + sqsum[1] + sqsum[2] + sqsum[3];
    const float mean = s * (1.0f / DD);
    const float var = q * (1.0f / DD) - mean * mean;
    const float rs = rsqrtf(var + 1e-5f);
    __hip_bfloat16* orow = out + (size_t)t * DD;
    orow[tid]       = __float2bfloat16((x0 - mean) * rs * g[tid]       + b[tid]);
    orow[tid + 256] = __float2bfloat16((x1 - mean) * rs * g[tid + 256] + b[tid + 256]);
    orow[tid + 512] = __float2bfloat16((x2 - mean) * rs * g[tid + 512] + b[tid + 512]);
}

__global__ __launch_bounds__(256) void ln_kernel(const float* __restrict__ in,
    const float* __restrict__ g, const float* __restrict__ b,
    __hip_bfloat16* __restrict__ out)
{
    __shared__ float ssum[4], sqsum[4];
    ln_body(in, g, b, out, blockIdx.x, threadIdx.x, ssum, sqsum);
}

// ------------------------------------------- castT body: fp32 [K,N] -> bf16 [N,K], 32x32 tile
__device__ __forceinline__ void castT_body(const float* __restrict__ in,
    __hip_bfloat16* __restrict__ out, int K, int N, int bx, int by, int tid,
    float (*tt)[33])
{
    const int n0 = bx << 5, k0 = by << 5;
    const int tx = tid & 31, ty = tid >> 5;
    #pragma unroll
    for (int i = 0; i < 32; i += 8)
        tt[ty + i][tx] = in[(size_t)(k0 + ty + i) * N + n0 + tx];
    __syncthreads();
    #pragma unroll
    for (int i = 0; i < 32; i += 8)
        out[(size_t)(n0 + ty + i) * K + k0 + tx] = __float2bfloat16(tt[tx][ty + i]);
}

// ------------------------------------------- fused phase-0 prep + ln1 (R21: launch fusion)
// grid 4569: [0,2048) ln1 | [2048,3776) qkv_w castT | [3776,4352) gvw castT | [4352,4569) wcat
__global__ __launch_bounds__(256) void fused0_kernel(
    const float* __restrict__ x, const float* __restrict__ ln1_g, const float* __restrict__ ln1_b,
    __hip_bfloat16* __restrict__ ln1,
    const float* __restrict__ qkv_w, const float* __restrict__ gvw,
    const float* __restrict__ w2w, const float* __restrict__ w1w,
    const float* __restrict__ w1r, const float* __restrict__ w2r,
    const float* __restrict__ gw, const float* __restrict__ qkv_b,
    const float* __restrict__ gvb,
    __hip_bfloat16* __restrict__ Bt, float* __restrict__ bias3)
{
    __shared__ float tt[32][33];
    const int bid = blockIdx.x;
    const int tid = threadIdx.x;
    if (bid < 2048) { ln_body(x, ln1_g, ln1_b, ln1, bid, tid, (float*)&tt[0][0], (float*)&tt[1][0]); return; }
    const int pb = bid - 2048;
    if (pb < 1728)      { castT_body(qkv_w, Bt, 768, 2304, pb % 72, pb / 72, tid, tt); return; }
    else if (pb < 2304) { int b = pb - 1728; castT_body(gvw, Bt + (size_t)2304 * 768, 768, 768, b % 24, b / 24, tid, tt); return; }
    const int wb = pb - 2304;
    if (wb >= 204) {   // bias concat: 13 blocks x 256 = 3328
        const int idx = (wb - 204) * 256 + tid;
        float v = (idx < 2304) ? qkv_b[idx] : ((idx < 3072) ? gvb[idx - 2304] : 0.f);
        bias3[idx] = v;
        return;
    }
    const float* src; int col, stride;
    if (wb < 48)       { src = w2w; col = wb;       stride = 48; }
    else if (wb < 96)  { src = w1w; col = wb - 48;  stride = 48; }
    else if (wb < 144) { src = w1r; col = wb - 96;  stride = 48; }
    else if (wb < 192) { src = w2r; col = wb - 144; stride = 48; }
    else               { src = gw;  col = wb - 192; stride = 12; }
    #pragma unroll
    for (int i = 0; i < 3; ++i) {
        const int k = tid + (i << 8);
        Bt[(size_t)(3072 + wb) * 768 + k] = __float2bfloat16(src[(size_t)k * stride + col]);
    }
}

// ------------------------------------------- phase-1 prep: ow/fcw/pw castT
// grid 5184: [0,576) ow->o0 | [576,2880) fcw->o1 | [2880,5184) pw->o2
__global__ __launch_bounds__(256) void prep1_kernel(
    const float* __restrict__ w0, const float* __restrict__ w1, const float* __restrict__ w2,
    __hip_bfloat16* __restrict__ o0, __hip_bfloat16* __restrict__ o1,
    __hip_bfloat16* __restrict__ o2)
{
    __shared__ float tt[32][33];
    const int bid = blockIdx.x;
    const int tid = threadIdx.x;
    if (bid < 576)       { castT_body(w0, o0, 768, 768, bid % 24, bid / 24, tid, tt); }
    else if (bid < 2880) { int b = bid - 576;  castT_body(w1, o1, 768, 3072, b % 96, b / 96, tid, tt); }
    else                 { int b = bid - 2880; castT_body(w2, o2, 3072, 768, b % 24, b / 24, tid, tt); }
}

// ---------------------------------------------------------------- MFMA GEMM (128x64 tile, BK=64)
// R26 = R12's mgemm verbatim (measured best: total 316.2 us). BK sweep
// closed: {32: 335.7, 64: 316.2, 96: 320.3}. BK=96 crossed the LDS
// occupancy tier (6 -> 4 blocks/CU), cancelling its drain savings --
// same failure mode as R7's 128x128, smaller magnitude. BK=64: drains
// 12/GEMM, LDS 24.6 KB, 6 blocks/CU by LDS, acc 32 VGPR.
__device__ __forceinline__ float gelu_f(float x) {
    float u = 0.7978845608028654f * (x + 0.044715f * x * x * x);
    return 0.5f * x * (1.0f + tanhf(u));
}

__global__ __launch_bounds__(256) void mgemm_kernel(
    const __hip_bfloat16* __restrict__ A, const __hip_bfloat16* __restrict__ Bt,
    const float* __restrict__ bias, const float* __restrict__ resid,
    void* __restrict__ Cout, float* __restrict__ Pb0, float* __restrict__ Pb1,
    int M, int N, int K, int kz, int epi, int omode)
{
    __shared__ __hip_bfloat16 As[2 * 128 * 32];
    __shared__ __hip_bfloat16 Bs[2 * 64 * 32];
    const int tid = threadIdx.x;
    const int lane = tid & 63, w = tid >> 6;
    const int colBase = blockIdx.x << 6, rowBase = blockIdx.y << 7;
    const int z = blockIdx.z;
    const int Kc = K / kz, koff = z * Kc;

    const int lr = lane >> 2, pc = lane & 3;
    const int n = lane & 15, quad = lane >> 4;

    const int sr0 = (w << 4) + lr;
    const int sr1 = 64 + sr0;
    const int sc0 = (pc ^ ((sr0 >> 1) & 3)) << 3;

    f32x4 acc[2][4];
    #pragma unroll
    for (int i = 0; i < 2; ++i)
        #pragma unroll
        for (int j = 0; j < 4; ++j) acc[i][j] = (f32x4){0.f, 0.f, 0.f, 0.f};

    const int ar0 = (w << 5) + n;
    const int ar1 = ar0 + 16;
    const int ap0 = (quad ^ ((ar0 >> 1) & 3)) << 3;
    const int ap1 = (quad ^ ((ar1 >> 1) & 3)) << 3;

    for (int kk = koff; kk < koff + Kc; kk += 64) {
        __syncthreads();
        // subtile 0 (k=kk) then subtile 1 (k=kk+32); layouts [2][128][32] / [2][64][32]
        gload16(A  + (size_t)(rowBase + sr0) * K + kk + sc0,      &As[(w << 4) * 32]);
        gload16(A  + (size_t)(rowBase + sr1) * K + kk + sc0,      &As[(64 + (w << 4)) * 32]);
        gload16(A  + (size_t)(rowBase + sr0) * K + kk + 32 + sc0, &As[(128 + (w << 4)) * 32]);
        gload16(A  + (size_t)(rowBase + sr1) * K + kk + 32 + sc0, &As[(192 + (w << 4)) * 32]);
        gload16(Bt + (size_t)(colBase + sr0) * K + kk + sc0,      &Bs[(w << 4) * 32]);
        gload16(Bt + (size_t)(colBase + sr0) * K + kk + 32 + sc0, &Bs[(64 + (w << 4)) * 32]);
        __syncthreads();

        #pragma unroll
        for (int s = 0; s < 2; ++s) {
            const int aoff = s << 12;           // s * 128 * 32
            const int boff = s << 11;           // s * 64 * 32
            bf16x8 a0 = *(const bf16x8*)&As[aoff + ar0 * 32 + ap0];
            bf16x8 a1 = *(const bf16x8*)&As[aoff + ar1 * 32 + ap1];
            #pragma unroll
            for (int j = 0; j < 4; ++j) {
                const int rb = (j << 4) + n;
                bf16x8 bfj = *(const bf16x8*)&Bs[boff + rb * 32 + ((quad ^ ((rb >> 1) & 3)) << 3)];
                acc[0][j] = __builtin_amdgcn_mfma_f32_16x16x32_bf16(a0, bfj, acc[0][j], 0, 0, 0);
                acc[1][j] = __builtin_amdgcn_mfma_f32_16x16x32_bf16(a1, bfj, acc[1][j], 0, 0, 0);
            }
        }
    }

    if (kz == 1) {
        #pragma unroll
        for (int j = 0; j < 4; ++j) {
            const int col = colBase + (j << 4) + n;
            const float bj = bias ? bias[col] : 0.f;
            #pragma unroll
            for (int i = 0; i < 2; ++i) {
                #pragma unroll
                for (int r = 0; r < 4; ++r) {
                    const int row = rowBase + (w << 5) + (i << 4) + (quad << 2) + r;
                    float v = acc[i][j][r] + bj;
                    if (epi == 1) v = gelu_f(v);
                    else if (epi == 2) v += resid[(size_t)row * N + col];
                    if (omode == 1) ((__hip_bfloat16*)Cout)[(size_t)row * N + col] = __float2bfloat16(v);
                    else ((float*)Cout)[(size_t)row * N + col] = v;
                }
            }
        }
    } else {
        float* P = (z == 0) ? Pb0 : Pb1;
        #pragma unroll
        for (int j = 0; j < 4; ++j) {
            const int col = colBase + (j << 4) + n;
            #pragma unroll
            for (int i = 0; i < 2; ++i) {
                #pragma unroll
                for (int r = 0; r < 4; ++r) {
                    const int row = rowBase + (w << 5) + (i << 4) + (quad << 2) + r;
                    P[(size_t)row * N + col] = acc[i][j][r];
                }
            }
        }
    }
}

// ------------------------------------------- split-K reduce: out = p0+p1+bias+resid (fp32)
__global__ __launch_bounds__(256) void kred_kernel(
    const float* __restrict__ p0, const float* __restrict__ p1,
    const float* __restrict__ bias, const float* __restrict__ resid,
    float* __restrict__ out, int N)
{
    const int base = (blockIdx.x * 256 + threadIdx.x) << 2;
    float4 a = *(const float4*)&p0[base];
    float4 b = *(const float4*)&p1[base];
    float4 bi = *(const float4*)&bias[base % N];
    float4 rs = *(const float4*)&resid[base];
    float4 o;
    o.x = a.x + b.x + bi.x + rs.x;
    o.y = a.y + b.y + bi.y + rs.y;
    o.z = a.z + b.z + bi.z + rs.z;
    o.w = a.w + b.w + bi.w + rs.w;
    *(float4*)&out[base] = o;
}

// ------------------------------------------------- exterior product helper
__device__ __forceinline__ void exterior6(const float* a, const float* b, float* L) {
    L[0] = a[0] * b[1] - a[1] * b[0];
    L[1] = a[0] * b[2] - a[2] * b[0];
    L[2] = a[0] * b[3] - a[3] * b[0];
    L[3] = a[1] * b[2] - a[2] * b[1];
    L[4] = a[1] * b[3] - a[3] * b[1];
    L[5] = a[2] * b[3] - a[3] * b[2];
    float n = sqrtf(L[0]*L[0] + L[1]*L[1] + L[2]*L[2] + L[3]*L[3] + L[4]*L[4] + L[5]*L[5]);
    float inv = 1.f / fmaxf(n, 1e-12f);
    #pragma unroll
    for (int p = 0; p < 6; ++p) L[p] *= inv;
}

// ------------------------------------------- fused extgate (4 tok/block) + vt (R21)
// grid 1280: [0,512) extgate x4 | [512,896) VT | [896,1280) GVT
__global__ __launch_bounds__(256) void fusedev_kernel(
    const __hip_bfloat16* __restrict__ qkvAll, const float* __restrict__ gb,
    __hip_bfloat16* __restrict__ rlb, __hip_bfloat16* __restrict__ jwb,
    float* __restrict__ gate,
    __hip_bfloat16* __restrict__ VT, __hip_bfloat16* __restrict__ GVT)
{
    __shared__ __hip_bfloat16 tile[64][72];
    const int bid = blockIdx.x;
    const int tid = threadIdx.x;
    if (bid < 512) {
        const int t = (bid << 2) | (tid >> 6);
        const int lane = tid & 63;
        const __hip_bfloat16* row = qkvAll + (size_t)t * 3328 + 3072;
        if (lane < 12) {
            const int h = lane;
            float a[4], b[4], L[6];
            #pragma unroll
            for (int i = 0; i < 4; ++i) {
                a[i] = (t > 0) ? __bfloat162float(row[-3328 + 48 + h * 4 + i]) : 0.f;
                b[i] = __bfloat162float(row[h * 4 + i]);
            }
            exterior6(a, b, L);
            __hip_bfloat16* jwp = jwb + (size_t)h * 16384 + t * 8;
            jwp[0] = __float2bfloat16( L[5]); jwp[1] = __float2bfloat16(-L[4]);
            jwp[2] = __float2bfloat16( L[3]); jwp[3] = __float2bfloat16( L[2]);
            jwp[4] = __float2bfloat16(-L[1]); jwp[5] = __float2bfloat16( L[0]);
            jwp[6] = __float2bfloat16(0.f);   jwp[7] = __float2bfloat16(0.f);
            #pragma unroll
            for (int i = 0; i < 4; ++i) {
                a[i] = __bfloat162float(row[96 + h * 4 + i]);
                b[i] = __bfloat162float(row[144 + h * 4 + i]);
            }
            exterior6(a, b, L);
            __hip_bfloat16* rlp = rlb + (size_t)h * 16384 + t * 8;
            #pragma unroll
            for (int p = 0; p < 6; ++p) rlp[p] = __float2bfloat16(L[p]);
            rlp[6] = __float2bfloat16(0.f); rlp[7] = __float2bfloat16(0.f);
        }
        if (lane == 32) {
            float g = 0.f;
            #pragma unroll
            for (int i = 0; i < 12; ++i)
                g += 1.f / (1.f + __expf(-(__bfloat162float(row[192 + i]) + gb[i])));
            gate[t] = g * (1.f / 12.f);
        }
        return;
    }
    // ---- vt part
    const int b = bid - 512;
    const bool isGV = (b >= 384);
    const int rem = isGV ? (b - 384) : b;
    const int h = rem >> 5;
    const int s0 = (rem & 31) << 6;
    const __hip_bfloat16* src = qkvAll + (isGV ? 2304 : 1536) + h * 64;
    __hip_bfloat16* dst = (isGV ? GVT : VT) + (size_t)h * 131072;
    const int r = tid >> 2, c = (tid & 3) << 3;
    *(bf16x8*)&tile[r][c]      = *(const bf16x8*)&src[(size_t)(s0 + r) * 3328 + c];
    *(bf16x8*)&tile[r][c + 32] = *(const bf16x8*)&src[(size_t)(s0 + r) * 3328 + c + 32];
    __syncthreads();
    __hip_bfloat16 tmp[8];
    #pragma unroll
    for (int j = 0; j < 8; ++j) tmp[j] = tile[c + j][r];
    *(bf16x8*)&dst[(size_t)r * 2048 + s0 + c] = *(const bf16x8*)tmp;
    #pragma unroll
    for (int j = 0; j < 8; ++j) tmp[j] = tile[c + 32 + j][r];
    *(bf16x8*)&dst[(size_t)r * 2048 + s0 + c + 32] = *(const bf16x8*)tmp;
}

// ---------------------------------------------------------------- MFMA dual-path flash attention
// R8's mattn verbatim (measured 55.4-55.6 us; staged pipeline load-bearing
// per R5 ablation; exp2f/cap-8 reverted per R10). 34.8 KB LDS, 4 blocks/CU.
__global__ __launch_bounds__(256) void mattn_kernel(
    const __hip_bfloat16* __restrict__ qkvAll, const __hip_bfloat16* __restrict__ VT,
    const __hip_bfloat16* __restrict__ GVT, const __hip_bfloat16* __restrict__ rlb,
    const __hip_bfloat16* __restrict__ jwb, const float* __restrict__ gate,
    const float* __restrict__ inc_scale, __hip_bfloat16* __restrict__ comb,
    __hip_bfloat16* __restrict__ OpA, __hip_bfloat16* __restrict__ OpB,
    __hip_bfloat16* __restrict__ OpC, float* __restrict__ stats)
{
    __shared__ __hip_bfloat16 Ks0[2048], Ks1[2048];
    __shared__ __hip_bfloat16 VTs0[2048], VTs1[2048];
    __shared__ __hip_bfloat16 GVTs0[2048], GVTs1[2048];
    __shared__ __hip_bfloat16 JWs[64][8];
    __shared__ __bf16 Ps[64][72];

    const int j = blockIdx.x;          // 0..73
    const int hh = blockIdx.y;
    int qt = 0, acc = 0, nc = 1;
    #pragma unroll 1
    for (;;) {
        nc = (qt + 9) / 9;             // ceil((qt+1)/9)
        if (j < acc + nc) break;
        acc += nc; ++qt;
    }
    const int c = j - acc;
    const int q0 = qt << 6;
    const int nk = qt + 1;
    const int ktb = c * nk / nc;
    const int kte = (c + 1) * nk / nc - 1;
    const int tid = threadIdx.x;
    const int w = tid >> 6, lane = tid & 63;
    const int n = lane & 15, quad = lane >> 4;

    const int qrow = q0 + (w << 4) + n;
    const size_t qb = (size_t)qrow * 3328 + hh * 64;
    bf16x8 af0 = *(const bf16x8*)&qkvAll[qb + (quad << 3)];
    bf16x8 af1 = *(const bf16x8*)&qkvAll[qb + 32 + (quad << 3)];
    bf16x8 rlA = zero8();
    if (quad == 0) rlA = *(const bf16x8*)&rlb[(size_t)hh * 16384 + (size_t)qrow * 8];
    const float isc = inc_scale[hh];
    const float mgc = fabsf(isc);
    const size_t vbase = (size_t)hh * 131072;

    const int sRow = tid >> 2, sc = tid & 3;
    const int sPos = ((sc ^ ((sRow >> 1) & 3)) << 3);
    const int sOff = sc << 3;

    f32x4 Os[4], Og[4];
    float m_s[4], lsp[4], lgp[4];
    #pragma unroll
    for (int r = 0; r < 4; ++r) {
        m_s[r] = -1e30f; lsp[r] = 0.f; lgp[r] = 0.f;
        Os[r] = (f32x4){0.f, 0.f, 0.f, 0.f};
        Og[r] = (f32x4){0.f, 0.f, 0.f, 0.f};
    }

    bf16x8 rK0, rK1, rV0, rV1, rG0, rG1, rJ = zero8();
    {
        const int k0 = ktb << 6;
        const size_t kb = (size_t)(k0 + sRow) * 3328 + 768 + hh * 64;
        const size_t vb = vbase + (size_t)sRow * 2048 + k0;
        rK0 = *(const bf16x8*)&qkvAll[kb + sOff];
        rK1 = *(const bf16x8*)&qkvAll[kb + sOff + 32];
        rV0 = *(const bf16x8*)&VT[vb + sOff];
        rV1 = *(const bf16x8*)&VT[vb + sOff + 32];
        rG0 = *(const bf16x8*)&GVT[vb + sOff];
        rG1 = *(const bf16x8*)&GVT[vb + sOff + 32];
        if (tid < 64) rJ = *(const bf16x8*)&jwb[(size_t)hh * 16384 + (size_t)(k0 + tid) * 8];
    }

    for (int kt = ktb; kt <= kte; ++kt) {
        const int k0 = kt << 6;
        __syncthreads();   // prior reads of LDS tiles done
        *(bf16x8*)&Ks0[sRow * 32 + sPos]  = rK0;
        *(bf16x8*)&Ks1[sRow * 32 + sPos]  = rK1;
        *(bf16x8*)&VTs0[sRow * 32 + sPos] = rV0;
        *(bf16x8*)&VTs1[sRow * 32 + sPos] = rV1;
        *(bf16x8*)&GVTs0[sRow * 32 + sPos] = rG0;
        *(bf16x8*)&GVTs1[sRow * 32 + sPos] = rG1;
        if (tid < 64) *(bf16x8*)&JWs[tid][0] = rJ;
        if (kt < kte) {
            const int k1 = (kt + 1) << 6;
            const size_t kb = (size_t)(k1 + sRow) * 3328 + 768 + hh * 64;
            const size_t vb = vbase + (size_t)sRow * 2048 + k1;
            rK0 = *(const bf16x8*)&qkvAll[kb + sOff];
            rK1 = *(const bf16x8*)&qkvAll[kb + sOff + 32];
            rV0 = *(const bf16x8*)&VT[vb + sOff];
            rV1 = *(const bf16x8*)&VT[vb + sOff + 32];
            rG0 = *(const bf16x8*)&GVT[vb + sOff];
            rG1 = *(const bf16x8*)&GVT[vb + sOff + 32];
            if (tid < 64) rJ = *(const bf16x8*)&jwb[(size_t)hh * 16384 + (size_t)(k1 + tid) * 8];
        }
        __syncthreads();   // LDS tiles ready

        // ---- S = QK^T (std) and RL*JW (geo)
        f32x4 Ss[4], Sg[4];
        #pragma unroll
        for (int t = 0; t < 4; ++t) {
            Ss[t] = (f32x4){0.f, 0.f, 0.f, 0.f};
            Sg[t] = (f32x4){0.f, 0.f, 0.f, 0.f};
        }
        #pragma unroll
        for (int t = 0; t < 4; ++t) {
            const int krow = (t << 4) + n;
            const int kpos = ((quad ^ ((krow >> 1) & 3)) << 3);
            bf16x8 kb0 = *(const bf16x8*)&Ks0[krow * 32 + kpos];
            bf16x8 kb1 = *(const bf16x8*)&Ks1[krow * 32 + kpos];
            Ss[t] = __builtin_amdgcn_mfma_f32_16x16x32_bf16(af0, kb0, Ss[t], 0, 0, 0);
            Ss[t] = __builtin_amdgcn_mfma_f32_16x16x32_bf16(af1, kb1, Ss[t], 0, 0, 0);
            bf16x8 jb = zero8();
            if (quad == 0) jb = *(const bf16x8*)&JWs[krow][0];
            Sg[t] = __builtin_amdgcn_mfma_f32_16x16x32_bf16(rlA, jb, Sg[t], 0, 0, 0);
        }
        #pragma unroll
        for (int t = 0; t < 4; ++t) {
            #pragma unroll
            for (int r = 0; r < 4; ++r) { Ss[t][r] *= 0.125f; Sg[t][r] *= isc; }
        }
        if (kt == qt) {
            #pragma unroll
            for (int t = 0; t < 4; ++t) {
                const int sg = k0 + (t << 4) + n;
                #pragma unroll
                for (int r = 0; r < 4; ++r) {
                    const int qg = q0 + (w << 4) + (quad << 2) + r;
                    if (sg > qg) { Ss[t][r] = -1e30f; Sg[t][r] = -1e30f; }
                }
            }
        }

        // ---- softmax: std max-reduce; sums lane-local
        #pragma unroll
        for (int r = 0; r < 4; ++r) {
            float mx = fmaxf(fmaxf(Ss[0][r], Ss[1][r]), fmaxf(Ss[2][r], Ss[3][r]));
            #pragma unroll
            for (int mk = 1; mk < 16; mk <<= 1) mx = fmaxf(mx, __shfl_xor(mx, mk));
            float mnew = fmaxf(m_s[r], mx);
            float alpha = __expf(m_s[r] - mnew);
            m_s[r] = mnew;
            float sm = 0.f;
            #pragma unroll
            for (int t = 0; t < 4; ++t) { Ss[t][r] = __expf(Ss[t][r] - mnew); sm += Ss[t][r]; }
            lsp[r] = lsp[r] * alpha + sm;
            #pragma unroll
            for (int t = 0; t < 4; ++t) Os[t][r] *= alpha;

            float smg = 0.f;
            #pragma unroll
            for (int t = 0; t < 4; ++t) { Sg[t][r] = __expf(Sg[t][r] - mgc); smg += Sg[t][r]; }
            lgp[r] += smg;
        }

        // ---- std P -> LDS (wave-local), fence, std PV
        #pragma unroll
        for (int t = 0; t < 4; ++t) {
            #pragma unroll
            for (int r = 0; r < 4; ++r)
                Ps[(w << 4) + (quad << 2) + r][(t << 4) + n] = (__bf16)Ss[t][r];
        }
        asm volatile("s_waitcnt lgkmcnt(0)" ::: "memory");
        #pragma unroll
        for (int st = 0; st < 2; ++st) {
            bf16x8 ap = *(const bf16x8*)&Ps[(w << 4) + n][(st << 5) + (quad << 3)];
            const __hip_bfloat16* Vh = st ? VTs1 : VTs0;
            #pragma unroll
            for (int dt = 0; dt < 4; ++dt) {
                const int vrow = (dt << 4) + n;
                const int vpos = ((quad ^ ((vrow >> 1) & 3)) << 3);
                bf16x8 vb2 = *(const bf16x8*)&Vh[vrow * 32 + vpos];
                Os[dt] = __builtin_amdgcn_mfma_f32_16x16x32_bf16(ap, vb2, Os[dt], 0, 0, 0);
            }
        }
        asm volatile("s_waitcnt lgkmcnt(0)" ::: "memory");   // P reads drained before overwrite

        // ---- geo P -> same LDS buffer, fence, geo PV
        #pragma unroll
        for (int t = 0; t < 4; ++t) {
            #pragma unroll
            for (int r = 0; r < 4; ++r)
                Ps[(w << 4) + (quad << 2) + r][(t << 4) + n] = (__bf16)Sg[t][r];
        }
        asm volatile("s_waitcnt lgkmcnt(0)" ::: "memory");
        #pragma unroll
        for (int st = 0; st < 2; ++st) {
            bf16x8 gp = *(const bf16x8*)&Ps[(w << 4) + n][(st << 5) + (quad << 3)];
            const __hip_bfloat16* Gh = st ? GVTs1 : GVTs0;
            #pragma unroll
            for (int dt = 0; dt < 4; ++dt) {
                const int vrow = (dt << 4) + n;
                const int vpos = ((quad ^ ((vrow >> 1) & 3)) << 3);
                bf16x8 gb2 = *(const bf16x8*)&Gh[vrow * 32 + vpos];
                Og[dt] = __builtin_amdgcn_mfma_f32_16x16x32_bf16(gp, gb2, Og[dt], 0, 0, 0);
            }
        }
    }

    // ---- final l_s / l_g reduction
    float l_s[4], l_g[4];
    #pragma unroll
    for (int r = 0; r < 4; ++r) {
        float ls = lsp[r], lg = lgp[r];
        #pragma unroll
        for (int mk = 1; mk < 16; mk <<= 1) {
            ls += __shfl_xor(ls, mk);
            lg += __shfl_xor(lg, mk);
        }
        l_s[r] = ls; l_g[r] = lg;
    }

    if (nc == 1) {
        #pragma unroll
        for (int r = 0; r < 4; ++r) {
            const int row = q0 + (w << 4) + (quad << 2) + r;
            const float g = gate[row];
            const float invs = (1.f - g) / l_s[r], invg = g / l_g[r];
            #pragma unroll
            for (int dt = 0; dt < 4; ++dt) {
                float val = Os[dt][r] * invs + Og[dt][r] * invg;
                comb[(size_t)row * DD + hh * 64 + (dt << 4) + n] = __float2bfloat16(val);
            }
        }
    } else {
        const int slot = hh * 74 + acc + c;
        __hip_bfloat16* op = (__hip_bfloat16*)opart_cptr(OpA, OpB, OpC, slot);
        float* st = stats + (size_t)slot * 256;
        #pragma unroll
        for (int r = 0; r < 4; ++r) {
            const int rloc = (w << 4) + (quad << 2) + r;
            #pragma unroll
            for (int dt = 0; dt < 4; ++dt) {
                const int col = (dt << 4) + n;
                op[rloc * 128 + col]      = __float2bfloat16(Os[dt][r]);
                op[rloc * 128 + 64 + col] = __float2bfloat16(Og[dt][r]);
            }
            if (n == 0) {
                st[rloc * 4 + 0] = m_s[r]; st[rloc * 4 + 1] = l_s[r];
                st[rloc * 4 + 2] = mgc;    st[rloc * 4 + 3] = l_g[r];
            }
        }
    }
}

// ------------------------------------------- combine 2-4 K-chunks (qt>=9)
__global__ __launch_bounds__(256) void acomb_kernel(
    const __hip_bfloat16* __restrict__ OpA, const __hip_bfloat16* __restrict__ OpB,
    const __hip_bfloat16* __restrict__ OpC, const float* __restrict__ stats,
    const float* __restrict__ gate, __hip_bfloat16* __restrict__ comb)
{
    const int qt = 9 + blockIdx.x;     // 9..31
    const int h = blockIdx.y;
    const int nc = (qt + 9) / 9;       // 2..4
    int acc = 0;
    #pragma unroll 1
    for (int q = 0; q < qt; ++q) acc += (q + 9) / 9;
    const int sb = h * 74 + acc;
    const int tid = threadIdx.x;
    const int rloc = tid >> 2;
    const int cseg = (tid & 3) << 4;
    const int row = (qt << 6) + rloc;
    float ms = -1e30f, mg = -1e30f;
    for (int c = 0; c < nc; ++c) {
        const float* st = stats + (size_t)(sb + c) * 256 + rloc * 4;
        ms = fmaxf(ms, st[0]);
        mg = fmaxf(mg, st[2]);
    }
    float wsc[4], wgc[4];
    float ls = 0.f, lg = 0.f;
    for (int c = 0; c < nc; ++c) {
        const float* st = stats + (size_t)(sb + c) * 256 + rloc * 4;
        wsc[c] = __expf(st[0] - ms); ls += st[1] * wsc[c];
        wgc[c] = __expf(st[2] - mg); lg += st[3] * wgc[c];
    }
    const float g = gate[row];
    const float fs = (1.f - g) / ls, fg = g / lg;
    #pragma unroll
    for (int cc = 0; cc < 16; ++cc) {
        const int col = cseg + cc;
        float os = 0.f, og = 0.f;
        for (int c = 0; c < nc; ++c) {
            const __hip_bfloat16* op = opart_cptr(OpA, OpB, OpC, sb + c) + rloc * 128;
            os += __bfloat162float(op[col]) * wsc[c];
            og += __bfloat162float(op[64 + col]) * wgc[c];
        }
        comb[(size_t)row * DD + h * 64 + col] = __float2bfloat16(os * fs + og * fg);
    }
}

// ---------------------------------------------------------------- launch
extern "C" void kernel_launch(void* const* d_in, const int* in_sizes, int n_in,
                              void* d_out, int out_size, void* d_ws, size_t ws_size,
                              hipStream_t stream) {
    (void)in_sizes; (void)n_in; (void)out_size; (void)ws_size;
    const float* x      = (const float*)d_in[0];
    const float* ln1_g  = (const float*)d_in[1];
    const float* ln1_b  = (const float*)d_in[2];
    const float* qkv_w  = (const float*)d_in[3];
    const float* qkv_b  = (const float*)d_in[4];
    const float* w1w    = (const float*)d_in[5];
    const float* w2w    = (const float*)d_in[6];
    const float* w1r    = (const float*)d_in[7];
    const float* w2r    = (const float*)d_in[8];
    const float* gvw    = (const float*)d_in[9];
    const float* gvb    = (const float*)d_in[10];
    const float* gw     = (const float*)d_in[11];
    const float* gb     = (const float*)d_in[12];
    const float* isc    = (const float*)d_in[13];
    const float* ow     = (const float*)d_in[14];
    const float* ob     = (const float*)d_in[15];
    const float* ln2_g  = (const float*)d_in[16];
    const float* ln2_b  = (const float*)d_in[17];
    const float* fcw    = (const float*)d_in[18];
    const float* fcb    = (const float*)d_in[19];
    const float* pw     = (const float*)d_in[20];
    const float* pb     = (const float*)d_in[21];
    float* out = (float*)d_out;
    char* wsb  = (char*)d_ws;

    // ---- workspace layout
    __hip_bfloat16* qkvAll = (__hip_bfloat16*)(wsb + 0);         // 2048x3328 bf16 = 13631488
    __hip_bfloat16* VTb    = (__hip_bfloat16*)(wsb + 13631488);  // 3145728
    __hip_bfloat16* GVTb   = (__hip_bfloat16*)(wsb + 16777216);  // 3145728
    __hip_bfloat16* rlb    = (__hip_bfloat16*)(wsb + 19922944);  // 393216
    __hip_bfloat16* jwb    = (__hip_bfloat16*)(wsb + 20316160);  // 393216
    float*          gate   = (float*)(wsb + 20709376);           // 8192
    __hip_bfloat16* ln1    = (__hip_bfloat16*)(wsb + 20717568);  // 3145728
    __hip_bfloat16* comb   = (__hip_bfloat16*)(wsb + 23863296);  // 3145728
    float*          hbuf   = (float*)(wsb + 27009024);           // 6291456
    __hip_bfloat16* Bt     = (__hip_bfloat16*)(wsb + 33300480);  // 3328x768 bf16 = 5111808
    float*          bias3  = (float*)(wsb + 38412288);           // 13312
    __hip_bfloat16* owt    = (__hip_bfloat16*)(wsb + 38425600);  // 1179648

    // attention-phase aliases (ln1 / hbuf / Bt dead during attention)
    __hip_bfloat16* OpA   = ln1;                   // slots [0,192)
    __hip_bfloat16* OpB   = (__hip_bfloat16*)hbuf; // slots [192,576)
    __hip_bfloat16* OpC   = Bt;                    // slots [576,888)
    float*          stats = (float*)owt;           // 888*1KB = 909312 <= 1179648

    // MLP-phase aliases
    __hip_bfloat16* fcact  = qkvAll;                             // 2048x3072 bf16 = 12582912
    __hip_bfloat16* pwt    = VTb;                                // 768x3072 bf16 = 4718592
    __hip_bfloat16* fcwt   = Bt;                                 // 3072x768 bf16 = 4718592
    float* Ppart0 = (float*)(wsb + 20717568);                    // ln1+comb = 6291456
    float* Ppart1 = (float*)(wsb + 33300480);                    // Bt..owt  = 6291456

    // fused phase-0 prep + ln1
    fused0_kernel<<<4569, 256, 0, stream>>>(x, ln1_g, ln1_b, ln1,
                                            qkv_w, gvw, w2w, w1w, w1r, w2r, gw, qkv_b, gvb,
                                            Bt, bias3);
    // fused qkv + geo_v + small-proj GEMM: [2048,768] x [768,3328] -> bf16
    mgemm_kernel<<<dim3(52, 16, 1), 256, 0, stream>>>(ln1, Bt, bias3, nullptr, qkvAll,
                                                      nullptr, nullptr, TT, 3328, 768, 1, 0, 1);
    // fused extgate + vt
    fusedev_kernel<<<1280, 256, 0, stream>>>(qkvAll, gb, rlb, jwb, gate, VTb, GVTb);
    mattn_kernel<<<dim3(74, 12), 256, 0, stream>>>(qkvAll, VTb, GVTb, rlb, jwb, gate, isc,
                                                   comb, OpA, OpB, OpC, stats);
    acomb_kernel<<<dim3(23, 12), 256, 0, stream>>>(OpA, OpB, OpC, stats, gate, comb);
    // phase-1 prep (after acomb: Bt/owt regions die)
    prep1_kernel<<<5184, 256, 0, stream>>>(ow, fcw, pw, owt, fcwt, pwt);
    mgemm_kernel<<<dim3(12, 16, 1), 256, 0, stream>>>(comb, owt, ob, x, hbuf,
                                                      nullptr, nullptr, TT, 768, 768, 1, 2, 0);
    ln_kernel<<<TT, 256, 0, stream>>>(hbuf, ln2_g, ln2_b, ln1);
    mgemm_kernel<<<dim3(48, 16, 1), 256, 0, stream>>>(ln1, fcwt, fcb, nullptr, fcact,
                                                      nullptr, nullptr, TT, 3072, 768, 1, 1, 1);
    mgemm_kernel<<<dim3(12, 16, 2), 256, 0, stream>>>(fcact, pwt, pb, nullptr, nullptr,
                                                      Ppart0, Ppart1, TT, 768, 3072, 2, 0, 0);
    kred_kernel<<<1536, 256, 0, stream>>>(Ppart0, Ppart1, pb, hbuf, out, 768);
}